// Round 8
// baseline (587.051 us; speedup 1.0000x reference)
//
#include <hip/hip_runtime.h>
#include <hip/hip_bf16.h>

#define N   128
#define N3  (N*N*N)
#define M   64
#define M3  (M*M*M)
#define NPTS 65536
#define PD  66
#define PD2 (PD*PD)
#define PVOX (PD*PD*PD)
#define PH  130
#define PH2 (PH*PH)
#define PH3 (PH*PH*PH)

// float offsets inside the converted-weights buffer
enum : int {
  OW0A = 0,                 // 16*3*27   = 1296
  OW0B = 1296,              // 16*16*27  = 6912
  OWD0 = 8208,              // 32*16*27  = 13824
  OW1A = 22032,             // 32*32*27  = 27648
  OW1B = 49680,             // 32*32*27  = 27648
  OS0A = 77328, OB0A = 77344,
  OS0B = 77360, OB0B = 77376,
  OSD0 = 77392, OBD0 = 77424,
  OS1A = 77456, OB1A = 77488,
  OS1B = 77520, OB1B = 77552,
  WTOT = 77584
};

typedef short bf16x8 __attribute__((ext_vector_type(8)));
typedef float f32x4  __attribute__((ext_vector_type(4)));

__device__ __forceinline__ unsigned short f2bf_bits(float f) {
  __hip_bfloat16 b = __float2bfloat16(f);
  union { __hip_bfloat16 b; unsigned short u; } cv; cv.b = b; return cv.u;
}
__device__ __forceinline__ float bfbits2f(short s) {
  union { unsigned u; float f; } c; c.u = ((unsigned)(unsigned short)s) << 16; return c.f;
}

__device__ __forceinline__ float ldIn(const void* p, long i, int bf) {
  return bf ? __bfloat162float(((const __hip_bfloat16*)p)[i]) : ((const float*)p)[i];
}

// ---- dtype probe ----
__global__ void probe_k(const unsigned* __restrict__ s0a_raw, int* __restrict__ flag) {
  if (threadIdx.x == 0 && blockIdx.x == 0) {
    int all = 1;
    for (int i = 0; i < 8; ++i) {
      unsigned w = s0a_raw[i];
      if (((w >> 8) & 0xFFu) != 0x3Fu) all = 0;
    }
    *flag = all;
  }
}

// ---- convert all weights/scales/shifts to one fp32 buffer ----
__global__ __launch_bounds__(256) void cvt_k(
    const void* w0a, const void* w0b, const void* wd0,
    const void* w1a, const void* w1b,
    const void* s0a, const void* b0a,
    const void* s0b, const void* b0b,
    const void* sd0, const void* bd0,
    const void* s1a, const void* b1a,
    const void* s1b, const void* b1b,
    const int* __restrict__ flag, float* __restrict__ wbuf)
{
  int i = blockIdx.x * 256 + threadIdx.x;
  if (i >= WTOT) return;
  int bf = *flag;
  const void* src; int off;
  if      (i < OW0B) { src = w0a; off = OW0A; }
  else if (i < OWD0) { src = w0b; off = OW0B; }
  else if (i < OW1A) { src = wd0; off = OWD0; }
  else if (i < OW1B) { src = w1a; off = OW1A; }
  else if (i < OS0A) { src = w1b; off = OW1B; }
  else if (i < OB0A) { src = s0a; off = OS0A; }
  else if (i < OS0B) { src = b0a; off = OB0A; }
  else if (i < OB0B) { src = s0b; off = OS0B; }
  else if (i < OSD0) { src = b0b; off = OB0B; }
  else if (i < OBD0) { src = sd0; off = OSD0; }
  else if (i < OS1A) { src = bd0; off = OBD0; }
  else if (i < OB1A) { src = s1a; off = OS1A; }
  else if (i < OS1B) { src = b1a; off = OB1A; }
  else if (i < OB1B) { src = s1b; off = OS1B; }
  else               { src = b1b; off = OB1B; }
  wbuf[i] = ldIn(src, i - off, bf);
}

// ---- transpose conv0b/convd0 weights to [tap][ic][oc] ----
__global__ __launch_bounds__(256) void wtrans_k(const float* __restrict__ wbuf,
                                               float* __restrict__ T0B,
                                               float* __restrict__ TD0)
{
  int i = blockIdx.x * 256 + threadIdx.x;
  if (i < 27 * 256) {
    int k = i >> 8, r = i & 255, ic = r >> 4, oc = r & 15;
    T0B[i] = wbuf[OW0B + (oc * 16 + ic) * 27 + k];
  }
  if (i < 27 * 512) {
    int k = i / 512, r = i % 512, ic = r >> 5, oc = r & 31;
    TD0[i] = wbuf[OWD0 + (oc * 16 + ic) * 27 + k];
  }
}

// ---- active-voxel list: one global atomic per block ----
__global__ __launch_bounds__(256) void masklist_k(const int* __restrict__ mask,
                                                  int* __restrict__ list,
                                                  int* __restrict__ cnt)
{
  __shared__ int lpos, lbase;
  int t = threadIdx.x;
  int start = blockIdx.x * 8192;
  if (t == 0) lpos = 0;
  __syncthreads();
  int myc = 0;
  #pragma unroll 4
  for (int i = 0; i < 32; ++i) myc += (mask[start + i * 256 + t] != 0);
  atomicAdd(&lpos, myc);
  __syncthreads();
  if (t == 0) { lbase = atomicAdd(cnt, lpos); lpos = 0; }
  __syncthreads();
  #pragma unroll 4
  for (int i = 0; i < 32; ++i) {
    int idx = start + i * 256 + t;
    if (mask[idx]) {
      int p = atomicAdd(&lpos, 1);
      list[lbase + p] = idx;
    }
  }
}

// ---- m1f = float(maxpool3d(mask, 3, stride 2, pad 1)) ----
__global__ __launch_bounds__(256) void dsmask_k(const int* __restrict__ mask,
                                                float* __restrict__ m1f)
{
  int idx = blockIdx.x * 256 + threadIdx.x;
  if (idx >= M3) return;
  int z = idx >> 12, y = (idx >> 6) & 63, x = idx & 63;
  int r = 0;
  #pragma unroll
  for (int dz = 0; dz < 3; ++dz) {
    int iz = 2 * z + dz - 1;
    if ((unsigned)iz >= 128u) continue;
    #pragma unroll
    for (int dy = 0; dy < 3; ++dy) {
      int iy = 2 * y + dy - 1;
      if ((unsigned)iy >= 128u) continue;
      #pragma unroll
      for (int dx = 0; dx < 3; ++dx) {
        int ix = 2 * x + dx - 1;
        if ((unsigned)ix >= 128u) continue;
        r |= mask[(iz << 14) | (iy << 7) | ix];
      }
    }
  }
  m1f[idx] = r ? 1.f : 0.f;
}

// ---- pack x_feat*mask into padded 130^3 channel-last 4ch bf16 ----
__global__ __launch_bounds__(256) void pack_k(const void* __restrict__ xf,
                                              const int* __restrict__ flag,
                                              const int* __restrict__ mask,
                                              short* __restrict__ xq)
{
  int idx = blockIdx.x * 256 + threadIdx.x;
  if (idx >= N3) return;
  int bf = *flag;
  int z = idx >> 14, y = (idx >> 7) & 127, x = idx & 127;
  union { unsigned short us[4]; uint2 v; } u;
  if (mask[idx]) {
    u.us[0] = f2bf_bits(ldIn(xf, idx, bf));
    u.us[1] = f2bf_bits(ldIn(xf, (long)N3 + idx, bf));
    u.us[2] = f2bf_bits(ldIn(xf, 2l * N3 + idx, bf));
  } else { u.us[0] = 0; u.us[1] = 0; u.us[2] = 0; }
  u.us[3] = 0;
  int pv = ((z + 1) * PH + (y + 1)) * PH + (x + 1);
  *(uint2*)(xq + (size_t)pv * 4) = u.v;
}

__device__ __forceinline__ int tap_shift_PH(int t) {
  if (t >= 27) return 0;
  int dz = t / 9, r9 = t - dz * 9, dy = r9 / 3, dx = r9 - dy * 3;
  return (dz - 1) * PH2 + (dy - 1) * PH + (dx - 1);
}

// ---- conv0a via MFMA over the active list: K = 28 taps x 4ch = 4 k-blocks ----
__global__ __launch_bounds__(256) void conv0a_mfma_k(
    const short* __restrict__ xq, const int* __restrict__ list,
    const int* __restrict__ cnt,
    const float* __restrict__ wbuf, short* __restrict__ h0p)
{
  __shared__ short ldsB[4 * 64 * 8];   // 4 KB
  int tid = threadIdx.x;
  for (int e = tid; e < 4 * 512; e += 256) {
    int kb = e >> 9, l = (e >> 3) & 63, j = e & 7;
    int k = ((l >> 4) << 3) + j;       // quad*8+j
    int tap = kb * 8 + (k >> 2), ch = k & 3, oc = l & 15;
    float v = (tap < 27 && ch < 3) ? wbuf[OW0A + (oc * 3 + ch) * 27 + tap] : 0.f;
    ldsB[e] = (short)f2bf_bits(v);
  }
  __syncthreads();
  int nact = *cnt;
  int wave = tid >> 6, lane = tid & 63, quad = lane >> 4, l15 = lane & 15;
  const int SAFE = PH2 + PH + 1;
  for (int base = blockIdx.x * 256; base < nact; base += 1024 * 256) {
    int i0 = base + wave * 64;
    int pv[4];
    #pragma unroll
    for (int tt = 0; tt < 4; ++tt) {
      int e2 = i0 + tt * 16 + l15;
      if (e2 < nact) {
        int idx = list[e2];
        int z = idx >> 14, y = (idx >> 7) & 127, x = idx & 127;
        pv[tt] = ((z + 1) * PH + (y + 1)) * PH + (x + 1);
      } else pv[tt] = SAFE;
    }
    f32x4 acc[4];
    #pragma unroll
    for (int tt = 0; tt < 4; ++tt) { f32x4 zf = {0.f,0.f,0.f,0.f}; acc[tt] = zf; }
    #pragma unroll
    for (int kb = 0; kb < 4; ++kb) {
      int t0 = kb * 8 + quad * 2, t1 = t0 + 1;
      int s0 = tap_shift_PH(t0), s1 = tap_shift_PH(t1);
      bf16x8 b = *(const bf16x8*)&ldsB[(kb * 64 + lane) * 8];
      #pragma unroll
      for (int tt = 0; tt < 4; ++tt) {
        union { struct { uint2 lo, hi; } p; bf16x8 v; } cv;
        cv.p.lo = *(const uint2*)(xq + (size_t)(pv[tt] + s0) * 4);
        cv.p.hi = *(const uint2*)(xq + (size_t)(pv[tt] + s1) * 4);
        acc[tt] = __builtin_amdgcn_mfma_f32_16x16x32_bf16(cv.v, b, acc[tt], 0, 0, 0);
      }
    }
    float sc = wbuf[OS0A + l15], sb = wbuf[OB0A + l15];
    #pragma unroll
    for (int tt = 0; tt < 4; ++tt)
      #pragma unroll
      for (int r = 0; r < 4; ++r) {
        int e2 = i0 + tt * 16 + quad * 4 + r;
        if (e2 < nact) {
          int idx = list[e2];
          int z = idx >> 14, y = (idx >> 7) & 127, x = idx & 127;
          int pvo = ((z + 1) * PH + (y + 1)) * PH + (x + 1);
          float vv = fmaxf(fmaf(acc[tt][r], sc, sb), 0.f);
          h0p[(size_t)pvo * 16 + l15] = (short)f2bf_bits(vv);
        }
      }
  }
}

// ---- conv0b via MFMA over the active list: 16ic -> 16oc, tap-pairs K=32 ----
__global__ __launch_bounds__(256) void conv0b_mfma_k(
    const short* __restrict__ h0p, const int* __restrict__ list,
    const int* __restrict__ cnt,
    const float* __restrict__ T0B, const float* __restrict__ wbuf,
    short* __restrict__ h1p)
{
  __shared__ short ldsB[14 * 64 * 8];   // 14 KB
  int tid = threadIdx.x;
  for (int e = tid; e < 14 * 512; e += 256) {
    int p = e >> 9, l = (e >> 3) & 63, j = e & 7;
    int kg = ((l >> 4) << 3) + j;
    int tap = 2 * p + (kg >> 4);
    int ic = kg & 15, oc = l & 15;
    ldsB[e] = (tap < 27) ? (short)f2bf_bits(T0B[tap * 256 + ic * 16 + oc]) : (short)0;
  }
  __syncthreads();
  int nact = *cnt;
  int wave = tid >> 6, lane = tid & 63, quad = lane >> 4, l15 = lane & 15;
  const int SAFE = PH2 + PH + 1;
  for (int base = blockIdx.x * 256; base < nact; base += 1024 * 256) {
    int i0 = base + wave * 64;
    int pv[4];
    #pragma unroll
    for (int tt = 0; tt < 4; ++tt) {
      int e2 = i0 + tt * 16 + l15;
      if (e2 < nact) {
        int idx = list[e2];
        int z = idx >> 14, y = (idx >> 7) & 127, x = idx & 127;
        pv[tt] = ((z + 1) * PH + (y + 1)) * PH + (x + 1);
      } else pv[tt] = SAFE;
    }
    f32x4 acc[4];
    #pragma unroll
    for (int tt = 0; tt < 4; ++tt) { f32x4 zf = {0.f,0.f,0.f,0.f}; acc[tt] = zf; }
    #pragma unroll
    for (int p = 0; p < 14; ++p) {
      const int t1 = 2 * p, t2 = (2 * p + 1 < 27) ? 2 * p + 1 : 2 * p;
      const int s1 = ((t1 / 9) - 1) * PH2 + (((t1 % 9) / 3) - 1) * PH + ((t1 % 3) - 1);
      const int s2 = ((t2 / 9) - 1) * PH2 + (((t2 % 9) / 3) - 1) * PH + ((t2 % 3) - 1);
      int sh = (quad >= 2) ? s2 : s1;
      bf16x8 b = *(const bf16x8*)&ldsB[(p * 64 + lane) * 8];
      #pragma unroll
      for (int tt = 0; tt < 4; ++tt) {
        bf16x8 a = *(const bf16x8*)(h0p + (size_t)(pv[tt] + sh) * 16 + ((quad & 1) << 3));
        acc[tt] = __builtin_amdgcn_mfma_f32_16x16x32_bf16(a, b, acc[tt], 0, 0, 0);
      }
    }
    float sc = wbuf[OS0B + l15], sb = wbuf[OB0B + l15];
    #pragma unroll
    for (int tt = 0; tt < 4; ++tt)
      #pragma unroll
      for (int r = 0; r < 4; ++r) {
        int e2 = i0 + tt * 16 + quad * 4 + r;
        if (e2 < nact) {
          int idx = list[e2];
          int z = idx >> 14, y = (idx >> 7) & 127, x = idx & 127;
          int pvo = ((z + 1) * PH + (y + 1)) * PH + (x + 1);
          float vv = fmaxf(fmaf(acc[tt][r], sc, sb), 0.f);
          h1p[(size_t)pvo * 16 + l15] = (short)f2bf_bits(vv);
        }
      }
  }
}

// ---- convd0 via MFMA: 16ic -> 32oc, stride 2, tap-pairs K=32 ----
__global__ __launch_bounds__(256) void convd0_mfma_k(
    const short* __restrict__ h1p, const float* __restrict__ m1f,
    const float* __restrict__ TD0, const float* __restrict__ wbuf,
    short* __restrict__ Pout)
{
  __shared__ short ldsB[14 * 2 * 64 * 8];   // 28 KB
  int tid = threadIdx.x;
  for (int e = tid; e < 14 * 1024; e += 256) {
    int p = e >> 10, h = (e >> 9) & 1, l = (e >> 3) & 63, j = e & 7;
    int kg = ((l >> 4) << 3) + j;
    int tap = 2 * p + (kg >> 4);
    int ic = kg & 15;
    int oc = (h << 4) + (l & 15);
    ldsB[e] = (tap < 27) ? (short)f2bf_bits(TD0[tap * 512 + ic * 32 + oc]) : (short)0;
  }
  __syncthreads();
  int wave = tid >> 6, lane = tid & 63, quad = lane >> 4, l15 = lane & 15;
  int rowid = blockIdx.x * 4 + wave;
  int z = rowid >> 6, y = rowid & 63;
  int base_row = ((2 * z) * PH + 2 * y) * PH;
  f32x4 acc[4][2];
  #pragma unroll
  for (int tt = 0; tt < 4; ++tt)
  #pragma unroll
  for (int h = 0; h < 2; ++h) { f32x4 zf = {0.f,0.f,0.f,0.f}; acc[tt][h] = zf; }
  #pragma unroll
  for (int p = 0; p < 14; ++p) {
    const int t1 = 2 * p, t2 = (2 * p + 1 < 27) ? 2 * p + 1 : 2 * p;
    const int s1 = (t1 / 9) * PH2 + ((t1 % 9) / 3) * PH + (t1 % 3);
    const int s2 = (t2 / 9) * PH2 + ((t2 % 9) / 3) * PH + (t2 % 3);
    int sh = (quad >= 2) ? s2 : s1;
    bf16x8 b0 = *(const bf16x8*)&ldsB[((p * 2 + 0) * 64 + lane) * 8];
    bf16x8 b1 = *(const bf16x8*)&ldsB[((p * 2 + 1) * 64 + lane) * 8];
    bf16x8 a[4];
    #pragma unroll
    for (int tt = 0; tt < 4; ++tt) {
      int vin = base_row + sh + 2 * (tt * 16 + l15);
      a[tt] = *(const bf16x8*)(h1p + (size_t)vin * 16 + ((quad & 1) << 3));
    }
    #pragma unroll
    for (int tt = 0; tt < 4; ++tt) {
      acc[tt][0] = __builtin_amdgcn_mfma_f32_16x16x32_bf16(a[tt], b0, acc[tt][0], 0, 0, 0);
      acc[tt][1] = __builtin_amdgcn_mfma_f32_16x16x32_bf16(a[tt], b1, acc[tt][1], 0, 0, 0);
    }
  }
  float sc[2] = { wbuf[OSD0 + l15], wbuf[OSD0 + 16 + l15] };
  float sb[2] = { wbuf[OBD0 + l15], wbuf[OBD0 + 16 + l15] };
  int mrow = (z * 64 + y) * 64;
  int obase = ((z + 1) * PD + (y + 1)) * PD + 1;
  #pragma unroll
  for (int tt = 0; tt < 4; ++tt) {
    float4 mv = *(const float4*)&m1f[mrow + tt * 16 + quad * 4];
    float mvr[4] = {mv.x, mv.y, mv.z, mv.w};
    #pragma unroll
    for (int h = 0; h < 2; ++h)
      #pragma unroll
      for (int r = 0; r < 4; ++r) {
        float vv = fmaxf(fmaf(acc[tt][h][r], sc[h], sb[h]), 0.f) * mvr[r];
        int vox = obase + tt * 16 + quad * 4 + r;
        Pout[(size_t)vox * 32 + h * 16 + l15] = (short)f2bf_bits(vv);
      }
  }
}

// ---- conv1 via MFMA implicit GEMM: 32->32 ch over padded 66^3 ----
// LDS holds taps 0..25 (52 KB -> 3 blocks/CU); tap 26's B-frags in VGPRs.
// 1 row per wave, 4 rows per block, grid = 1024 so 3 blocks/CU are reachable.
__global__ __launch_bounds__(256) void conv1_mfma_k(
    const short* __restrict__ Pin, short* __restrict__ Pout,
    const float* __restrict__ wbuf, int wof, int sof, int bof,
    const float* __restrict__ m1f)
{
  __shared__ short ldsB[26 * 2 * 64 * 8];   // 52 KB
  int tid = threadIdx.x;
  for (int e = tid; e < 26 * 1024; e += 256) {
    int t = e >> 10;
    int h = (e >> 9) & 1;
    int l = (e >> 3) & 63;
    int j = e & 7;
    int ic = ((l >> 4) << 3) + j;
    int oc = (h << 4) + (l & 15);
    ldsB[e] = (short)f2bf_bits(wbuf[wof + (oc * 32 + ic) * 27 + t]);
  }

  int wave = tid >> 6, lane = tid & 63;
  int quad = lane >> 4, l15 = lane & 15;

  // tap 26 B-fragments in registers (same lane mapping as ldsB)
  bf16x8 b26[2];
  #pragma unroll
  for (int h = 0; h < 2; ++h) {
    int oc = (h << 4) + l15;
    #pragma unroll
    for (int j = 0; j < 8; ++j)
      b26[h][j] = (short)f2bf_bits(wbuf[wof + (oc * 32 + (quad * 8 + j)) * 27 + 26]);
  }
  __syncthreads();

  f32x4 acc[4][2];
  #pragma unroll
  for (int tt = 0; tt < 4; ++tt)
  #pragma unroll
  for (int h = 0; h < 2; ++h) {
    f32x4 zf = {0.f, 0.f, 0.f, 0.f};
    acc[tt][h] = zf;
  }

  int rowid = blockIdx.x * 4 + wave;
  int zz = rowid >> 6, yy = rowid & 63;
  int abase = ((zz + 1) * PD + (yy + 1)) * PD + 1;

  #pragma unroll 1
  for (int k = 0; k < 27; ++k) {
    int dz = k / 9, r9 = k - dz * 9, dy = r9 / 3, dx = r9 - dy * 3;
    int shift = (dz - 1) * PD2 + (dy - 1) * PD + (dx - 1);
    bf16x8 b0, b1;
    if (k < 26) {
      b0 = *(const bf16x8*)&ldsB[((k * 2 + 0) * 64 + lane) * 8];
      b1 = *(const bf16x8*)&ldsB[((k * 2 + 1) * 64 + lane) * 8];
    } else {
      b0 = b26[0]; b1 = b26[1];
    }
    bf16x8 a[4];
    #pragma unroll
    for (int tt = 0; tt < 4; ++tt) {
      int off = (abase + shift + tt * 16 + l15) * 32 + quad * 8;
      a[tt] = *(const bf16x8*)(Pin + off);
    }
    #pragma unroll
    for (int tt = 0; tt < 4; ++tt) {
      acc[tt][0] = __builtin_amdgcn_mfma_f32_16x16x32_bf16(a[tt], b0, acc[tt][0], 0, 0, 0);
      acc[tt][1] = __builtin_amdgcn_mfma_f32_16x16x32_bf16(a[tt], b1, acc[tt][1], 0, 0, 0);
    }
  }

  float sc[2] = { wbuf[sof + l15], wbuf[sof + 16 + l15] };
  float sh[2] = { wbuf[bof + l15], wbuf[bof + 16 + l15] };

  int mrow = (zz * 64 + yy) * 64;
  #pragma unroll
  for (int tt = 0; tt < 4; ++tt) {
    const float4 mv = *(const float4*)&m1f[mrow + tt * 16 + quad * 4];
    float mvr[4] = {mv.x, mv.y, mv.z, mv.w};
    #pragma unroll
    for (int h = 0; h < 2; ++h) {
      #pragma unroll
      for (int r = 0; r < 4; ++r) {
        float v = fmaxf(fmaf(acc[tt][h][r], sc[h], sh[h]), 0.f) * mvr[r];
        int vox = abase + tt * 16 + quad * 4 + r;
        Pout[vox * 32 + h * 16 + l15] = (short)f2bf_bits(v);
      }
    }
  }
}

// ---- trilinear sample from padded channel-last bf16 volume ----
__global__ __launch_bounds__(256) void sample_k(
    const void* __restrict__ coords, const int* __restrict__ flag,
    const short* __restrict__ vol, void* __restrict__ out)
{
  int p = blockIdx.x * 256 + threadIdx.x;
  if (p >= NPTS) return;
  int bf = *flag;
  float cx = ldIn(coords, 3l * p + 0, bf);
  float cy = ldIn(coords, 3l * p + 1, bf);
  float cz = ldIn(coords, 3l * p + 2, bf);
  float fx = (cx + 1.f) * 0.5f * 63.f;
  float fy = (cy + 1.f) * 0.5f * 63.f;
  float fz = (cz + 1.f) * 0.5f * 63.f;
  float x0f = floorf(fx), y0f = floorf(fy), z0f = floorf(fz);
  int x0 = (int)x0f, y0 = (int)y0f, z0 = (int)z0f;
  float tx = fx - x0f, ty = fy - y0f, tz = fz - z0f;
  int li[8]; float wt[8];
  #pragma unroll
  for (int dz = 0; dz < 2; ++dz)
  #pragma unroll
  for (int dy = 0; dy < 2; ++dy)
  #pragma unroll
  for (int dx = 0; dx < 2; ++dx) {
    int t = dz * 4 + dy * 2 + dx;
    int xi = x0 + dx, yi = y0 + dy, zi = z0 + dz;
    bool ok = (unsigned)xi < 64u && (unsigned)yi < 64u && (unsigned)zi < 64u;
    int xc = min(max(xi, 0), 63), yc = min(max(yi, 0), 63), zc = min(max(zi, 0), 63);
    li[t] = ((zc + 1) * PD + (yc + 1)) * PD + (xc + 1);
    float w = (dx ? tx : 1.f - tx) * (dy ? ty : 1.f - ty) * (dz ? tz : 1.f - tz);
    wt[t] = ok ? w : 0.f;
  }
  #pragma unroll
  for (int cc = 0; cc < 4; ++cc) {
    float s[8];
    #pragma unroll
    for (int j = 0; j < 8; ++j) s[j] = 0.f;
    #pragma unroll
    for (int t = 0; t < 8; ++t) {
      bf16x8 v = *(const bf16x8*)(vol + (size_t)li[t] * 32 + cc * 8);
      #pragma unroll
      for (int j = 0; j < 8; ++j) s[j] += bfbits2f(v[j]) * wt[t];
    }
    if (bf) {
      union { unsigned short us[8]; uint4 v; } u;
      #pragma unroll
      for (int j = 0; j < 8; ++j) u.us[j] = f2bf_bits(s[j]);
      ((uint4*)out)[p * 4 + cc] = u.v;
    } else {
      #pragma unroll
      for (int j = 0; j < 8; ++j) ((float*)out)[(size_t)p * 32 + cc * 8 + j] = s[j];
    }
  }
}

extern "C" void kernel_launch(void* const* d_in, const int* in_sizes, int n_in,
                              void* d_out, int out_size, void* d_ws, size_t ws_size,
                              hipStream_t stream)
{
  const void* xf     = d_in[0];
  const int*  mask   = (const int*)d_in[1];
  const void* coords = d_in[2];
  const void* w0a = d_in[3];
  const void* s0a = d_in[4];
  const void* b0a = d_in[5];
  const void* w0b = d_in[6];
  const void* s0b = d_in[7];
  const void* b0b = d_in[8];
  const void* wd0 = d_in[9];
  const void* sd0 = d_in[10];
  const void* bd0 = d_in[11];
  const void* w1a = d_in[12];
  const void* s1a = d_in[13];
  const void* b1a = d_in[14];
  const void* w1b = d_in[15];
  const void* s1b = d_in[16];
  const void* b1b = d_in[17];

  char* ws = (char*)d_ws;
  size_t cur = 0;
  auto alloc = [&](size_t bytes) -> size_t {
    size_t o = cur; cur = (cur + bytes + 255) & ~(size_t)255; return o;
  };
  size_t o_flag = alloc(4);
  size_t o_cnt  = alloc(4);
  size_t o_m1f  = alloc((size_t)M3 * 4);
  size_t o_wbuf = alloc((size_t)WTOT * 4);
  size_t o_T0B  = alloc((size_t)27 * 256 * 4);
  size_t o_TD0  = alloc((size_t)27 * 512 * 4);
  size_t o_list = alloc((size_t)N3 * 4);
  size_t o_h0p  = alloc((size_t)PH3 * 16 * 2);    // 70 MB
  size_t o_h1p  = alloc((size_t)PH3 * 16 * 2);    // 70 MB
  size_t o_P1   = alloc((size_t)PVOX * 32 * 2);   // 18.4 MB
  size_t o_P2   = alloc((size_t)PVOX * 32 * 2);   // 18.4 MB (xq aliases its head)

  int*   flag = (int*)(ws + o_flag);
  int*   cnt  = (int*)(ws + o_cnt);
  float* m1f  = (float*)(ws + o_m1f);
  float* wbuf = (float*)(ws + o_wbuf);
  float* T0B  = (float*)(ws + o_T0B);
  float* TD0  = (float*)(ws + o_TD0);
  int*   list = (int*)(ws + o_list);
  short* h0p  = (short*)(ws + o_h0p);
  short* h1p  = (short*)(ws + o_h1p);
  short* P1   = (short*)(ws + o_P1);
  short* P2   = (short*)(ws + o_P2);
  short* xq   = (short*)(ws + o_P2);              // alias: xq (17.6 MB) in P2 region

  hipMemsetAsync(cnt, 0, 4, stream);
  // zero h0p + h1p + P1 + P2 (incl. xq halo) in one contiguous sweep (~177 MB)
  hipMemsetAsync(ws + o_h0p, 0,
                 (o_P2 - o_h0p) + (size_t)PVOX * 32 * 2, stream);

  probe_k<<<1, 64, 0, stream>>>((const unsigned*)s0a, flag);
  cvt_k<<<(WTOT + 255) / 256, 256, 0, stream>>>(w0a, w0b, wd0, w1a, w1b,
                                                s0a, b0a, s0b, b0b, sd0, bd0,
                                                s1a, b1a, s1b, b1b, flag, wbuf);
  wtrans_k<<<(27 * 512 + 255) / 256, 256, 0, stream>>>(wbuf, T0B, TD0);
  masklist_k<<<256, 256, 0, stream>>>(mask, list, cnt);
  dsmask_k<<<M3 / 256, 256, 0, stream>>>(mask, m1f);

  pack_k<<<N3 / 256, 256, 0, stream>>>(xf, flag, mask, xq);
  conv0a_mfma_k<<<1024, 256, 0, stream>>>(xq, list, cnt, wbuf, h0p);
  // xq dead; wipe P2 region (stale xq bytes would leak into P2's halo otherwise)
  hipMemsetAsync(ws + o_P2, 0, (size_t)PVOX * 32 * 2, stream);
  conv0b_mfma_k<<<1024, 256, 0, stream>>>(h0p, list, cnt, T0B, wbuf, h1p);
  convd0_mfma_k<<<1024, 256, 0, stream>>>(h1p, m1f, TD0, wbuf, P1);

  conv1_mfma_k<<<1024, 256, 0, stream>>>(P1, P2, wbuf, OW1A, OS1A, OB1A, m1f);
  conv1_mfma_k<<<1024, 256, 0, stream>>>(P2, P1, wbuf, OW1B, OS1B, OB1B, m1f);

  sample_k<<<NPTS / 256, 256, 0, stream>>>(coords, flag, P1, d_out);
}

// Round 9
// 368.254 us; speedup vs baseline: 1.5941x; 1.5941x over previous
//
#include <hip/hip_runtime.h>
#include <hip/hip_bf16.h>

#define N   128
#define N3  (N*N*N)
#define M   64
#define M3  (M*M*M)
#define NPTS 65536
#define PD  66
#define PD2 (PD*PD)
#define PVOX (PD*PD*PD)
#define PH  130
#define PH2 (PH*PH)
#define PH3 (PH*PH*PH)

// float offsets inside the converted-weights buffer
enum : int {
  OW0A = 0,                 // 16*3*27   = 1296
  OW0B = 1296,              // 16*16*27  = 6912
  OWD0 = 8208,              // 32*16*27  = 13824
  OW1A = 22032,             // 32*32*27  = 27648
  OW1B = 49680,             // 32*32*27  = 27648
  OS0A = 77328, OB0A = 77344,
  OS0B = 77360, OB0B = 77376,
  OSD0 = 77392, OBD0 = 77424,
  OS1A = 77456, OB1A = 77488,
  OS1B = 77520, OB1B = 77552,
  WTOT = 77584
};

// short offsets inside the bf16 LDS-image buffer
enum : int {
  IW0A = 0,       // 4*512   = 2048
  IW0B = 2048,    // 14*512  = 7168
  IWD0 = 9216,    // 14*1024 = 14336
  IW1A = 23552,   // 27*1024 = 27648
  IW1B = 51200,   // 27*1024 = 27648
  ITOT = 78848
};

typedef short bf16x8 __attribute__((ext_vector_type(8)));
typedef float f32x4  __attribute__((ext_vector_type(4)));

__device__ __forceinline__ unsigned short f2bf_bits(float f) {
  __hip_bfloat16 b = __float2bfloat16(f);
  union { __hip_bfloat16 b; unsigned short u; } cv; cv.b = b; return cv.u;
}
__device__ __forceinline__ float bfbits2f(short s) {
  union { unsigned u; float f; } c; c.u = ((unsigned)(unsigned short)s) << 16; return c.f;
}

__device__ __forceinline__ float ldIn(const void* p, long i, int bf) {
  return bf ? __bfloat162float(((const __hip_bfloat16*)p)[i]) : ((const float*)p)[i];
}

// ---- dtype probe ----
__global__ void probe_k(const unsigned* __restrict__ s0a_raw, int* __restrict__ flag) {
  if (threadIdx.x == 0 && blockIdx.x == 0) {
    int all = 1;
    for (int i = 0; i < 8; ++i) {
      unsigned w = s0a_raw[i];
      if (((w >> 8) & 0xFFu) != 0x3Fu) all = 0;
    }
    *flag = all;
  }
}

// ---- convert all weights/scales/shifts to one fp32 buffer ----
__global__ __launch_bounds__(256) void cvt_k(
    const void* w0a, const void* w0b, const void* wd0,
    const void* w1a, const void* w1b,
    const void* s0a, const void* b0a,
    const void* s0b, const void* b0b,
    const void* sd0, const void* bd0,
    const void* s1a, const void* b1a,
    const void* s1b, const void* b1b,
    const int* __restrict__ flag, float* __restrict__ wbuf)
{
  int i = blockIdx.x * 256 + threadIdx.x;
  if (i >= WTOT) return;
  int bf = *flag;
  const void* src; int off;
  if      (i < OW0B) { src = w0a; off = OW0A; }
  else if (i < OWD0) { src = w0b; off = OW0B; }
  else if (i < OW1A) { src = wd0; off = OWD0; }
  else if (i < OW1B) { src = w1a; off = OW1A; }
  else if (i < OS0A) { src = w1b; off = OW1B; }
  else if (i < OB0A) { src = s0a; off = OS0A; }
  else if (i < OS0B) { src = b0a; off = OB0A; }
  else if (i < OB0B) { src = s0b; off = OS0B; }
  else if (i < OSD0) { src = b0b; off = OB0B; }
  else if (i < OBD0) { src = sd0; off = OSD0; }
  else if (i < OS1A) { src = bd0; off = OBD0; }
  else if (i < OB1A) { src = s1a; off = OS1A; }
  else if (i < OS1B) { src = b1a; off = OB1A; }
  else if (i < OB1B) { src = s1b; off = OS1B; }
  else               { src = b1b; off = OB1B; }
  wbuf[i] = ldIn(src, i - off, bf);
}

// ---- build bf16 LDS images (exact per-kernel staging byte layout) ----
__global__ __launch_bounds__(256) void wtrans_k(const float* __restrict__ wbuf,
                                               short* __restrict__ WI)
{
  int i = blockIdx.x * 256 + threadIdx.x;
  if (i >= 27648) return;
  // conv0a image: [kb][lane][j], K = tap*4+ch over 4 k-blocks
  if (i < 2048) {
    int kb = i >> 9, l = (i >> 3) & 63, j = i & 7;
    int k = ((l >> 4) << 3) + j;
    int tap = kb * 8 + (k >> 2), ch = k & 3, oc = l & 15;
    float v = (tap < 27 && ch < 3) ? wbuf[OW0A + (oc * 3 + ch) * 27 + tap] : 0.f;
    WI[IW0A + i] = (short)f2bf_bits(v);
  }
  // conv0b image: [pair][lane][j]
  if (i < 7168) {
    int p = i >> 9, l = (i >> 3) & 63, j = i & 7;
    int kg = ((l >> 4) << 3) + j;
    int tap = 2 * p + (kg >> 4);
    int ic = kg & 15, oc = l & 15;
    float v = (tap < 27) ? wbuf[OW0B + (oc * 16 + ic) * 27 + tap] : 0.f;
    WI[IW0B + i] = (short)f2bf_bits(v);
  }
  // convd0 image: [pair][ochalf][lane][j]
  if (i < 14336) {
    int p = i >> 10, h = (i >> 9) & 1, l = (i >> 3) & 63, j = i & 7;
    int kg = ((l >> 4) << 3) + j;
    int tap = 2 * p + (kg >> 4);
    int ic = kg & 15;
    int oc = (h << 4) + (l & 15);
    float v = (tap < 27) ? wbuf[OWD0 + (oc * 16 + ic) * 27 + tap] : 0.f;
    WI[IWD0 + i] = (short)f2bf_bits(v);
  }
  // conv1 images: [tap][ochalf][lane][j]
  {
    int t = i >> 10, h = (i >> 9) & 1, l = (i >> 3) & 63, j = i & 7;
    int ic = ((l >> 4) << 3) + j;
    int oc = (h << 4) + (l & 15);
    WI[IW1A + i] = (short)f2bf_bits(wbuf[OW1A + (oc * 32 + ic) * 27 + t]);
    WI[IW1B + i] = (short)f2bf_bits(wbuf[OW1B + (oc * 32 + ic) * 27 + t]);
  }
}

// ---- active-voxel list: one global atomic per block ----
__global__ __launch_bounds__(256) void masklist_k(const int* __restrict__ mask,
                                                  int* __restrict__ list,
                                                  int* __restrict__ cnt)
{
  __shared__ int lpos, lbase;
  int t = threadIdx.x;
  int start = blockIdx.x * 8192;
  if (t == 0) lpos = 0;
  __syncthreads();
  int myc = 0;
  #pragma unroll 4
  for (int i = 0; i < 32; ++i) myc += (mask[start + i * 256 + t] != 0);
  atomicAdd(&lpos, myc);
  __syncthreads();
  if (t == 0) { lbase = atomicAdd(cnt, lpos); lpos = 0; }
  __syncthreads();
  #pragma unroll 4
  for (int i = 0; i < 32; ++i) {
    int idx = start + i * 256 + t;
    if (mask[idx]) {
      int p = atomicAdd(&lpos, 1);
      list[lbase + p] = idx;
    }
  }
}

// ---- m1f = float(maxpool3d(mask, 3, stride 2, pad 1)) ----
__global__ __launch_bounds__(256) void dsmask_k(const int* __restrict__ mask,
                                                float* __restrict__ m1f)
{
  int idx = blockIdx.x * 256 + threadIdx.x;
  if (idx >= M3) return;
  int z = idx >> 12, y = (idx >> 6) & 63, x = idx & 63;
  int r = 0;
  #pragma unroll
  for (int dz = 0; dz < 3; ++dz) {
    int iz = 2 * z + dz - 1;
    if ((unsigned)iz >= 128u) continue;
    #pragma unroll
    for (int dy = 0; dy < 3; ++dy) {
      int iy = 2 * y + dy - 1;
      if ((unsigned)iy >= 128u) continue;
      #pragma unroll
      for (int dx = 0; dx < 3; ++dx) {
        int ix = 2 * x + dx - 1;
        if ((unsigned)ix >= 128u) continue;
        r |= mask[(iz << 14) | (iy << 7) | ix];
      }
    }
  }
  m1f[idx] = r ? 1.f : 0.f;
}

// ---- pack x_feat*mask into padded 130^3 channel-last 4ch bf16 ----
__global__ __launch_bounds__(256) void pack_k(const void* __restrict__ xf,
                                              const int* __restrict__ flag,
                                              const int* __restrict__ mask,
                                              short* __restrict__ xq)
{
  int idx = blockIdx.x * 256 + threadIdx.x;
  if (idx >= N3) return;
  int bf = *flag;
  int z = idx >> 14, y = (idx >> 7) & 127, x = idx & 127;
  union { unsigned short us[4]; uint2 v; } u;
  if (mask[idx]) {
    u.us[0] = f2bf_bits(ldIn(xf, idx, bf));
    u.us[1] = f2bf_bits(ldIn(xf, (long)N3 + idx, bf));
    u.us[2] = f2bf_bits(ldIn(xf, 2l * N3 + idx, bf));
  } else { u.us[0] = 0; u.us[1] = 0; u.us[2] = 0; }
  u.us[3] = 0;
  int pv = ((z + 1) * PH + (y + 1)) * PH + (x + 1);
  *(uint2*)(xq + (size_t)pv * 4) = u.v;
}

__device__ __forceinline__ int tap_shift_PH(int t) {
  if (t >= 27) return 0;
  int dz = t / 9, r9 = t - dz * 9, dy = r9 / 3, dx = r9 - dy * 3;
  return (dz - 1) * PH2 + (dy - 1) * PH + (dx - 1);
}

// ---- conv0a via MFMA over the active list: K = 28 taps x 4ch = 4 k-blocks ----
__global__ __launch_bounds__(256) void conv0a_mfma_k(
    const short* __restrict__ xq, const int* __restrict__ list,
    const int* __restrict__ cnt, const short* __restrict__ WI,
    const float* __restrict__ wbuf, short* __restrict__ h0p)
{
  __shared__ short ldsB[4 * 512];   // 4 KB
  int tid = threadIdx.x;
  if (tid < 256) ((uint4*)ldsB)[tid] = ((const uint4*)(WI + IW0A))[tid];
  __syncthreads();
  int nact = *cnt;
  int wave = tid >> 6, lane = tid & 63, quad = lane >> 4, l15 = lane & 15;
  const int SAFE = PH2 + PH + 1;
  for (int base = blockIdx.x * 256; base < nact; base += 1024 * 256) {
    int i0 = base + wave * 64;
    int pv[4];
    #pragma unroll
    for (int tt = 0; tt < 4; ++tt) {
      int e2 = i0 + tt * 16 + l15;
      if (e2 < nact) {
        int idx = list[e2];
        int z = idx >> 14, y = (idx >> 7) & 127, x = idx & 127;
        pv[tt] = ((z + 1) * PH + (y + 1)) * PH + (x + 1);
      } else pv[tt] = SAFE;
    }
    f32x4 acc[4];
    #pragma unroll
    for (int tt = 0; tt < 4; ++tt) { f32x4 zf = {0.f,0.f,0.f,0.f}; acc[tt] = zf; }
    #pragma unroll
    for (int kb = 0; kb < 4; ++kb) {
      int t0 = kb * 8 + quad * 2, t1 = t0 + 1;
      int s0 = tap_shift_PH(t0), s1 = tap_shift_PH(t1);
      bf16x8 b = *(const bf16x8*)&ldsB[(kb * 64 + lane) * 8];
      #pragma unroll
      for (int tt = 0; tt < 4; ++tt) {
        union { struct { uint2 lo, hi; } p; bf16x8 v; } cv;
        cv.p.lo = *(const uint2*)(xq + (size_t)(pv[tt] + s0) * 4);
        cv.p.hi = *(const uint2*)(xq + (size_t)(pv[tt] + s1) * 4);
        acc[tt] = __builtin_amdgcn_mfma_f32_16x16x32_bf16(cv.v, b, acc[tt], 0, 0, 0);
      }
    }
    float sc = wbuf[OS0A + l15], sb = wbuf[OB0A + l15];
    #pragma unroll
    for (int tt = 0; tt < 4; ++tt)
      #pragma unroll
      for (int r = 0; r < 4; ++r) {
        int e2 = i0 + tt * 16 + quad * 4 + r;
        if (e2 < nact) {
          int idx = list[e2];
          int z = idx >> 14, y = (idx >> 7) & 127, x = idx & 127;
          int pvo = ((z + 1) * PH + (y + 1)) * PH + (x + 1);
          float vv = fmaxf(fmaf(acc[tt][r], sc, sb), 0.f);
          h0p[(size_t)pvo * 16 + l15] = (short)f2bf_bits(vv);
        }
      }
  }
}

// ---- conv0b via MFMA over the active list: 16ic -> 16oc, tap-pairs K=32 ----
__global__ __launch_bounds__(256) void conv0b_mfma_k(
    const short* __restrict__ h0p, const int* __restrict__ list,
    const int* __restrict__ cnt, const short* __restrict__ WI,
    const float* __restrict__ wbuf, short* __restrict__ h1p)
{
  __shared__ short ldsB[14 * 512];   // 14 KB
  int tid = threadIdx.x;
  for (int i = tid; i < 14 * 64; i += 256)
    ((uint4*)ldsB)[i] = ((const uint4*)(WI + IW0B))[i];
  __syncthreads();
  int nact = *cnt;
  int wave = tid >> 6, lane = tid & 63, quad = lane >> 4, l15 = lane & 15;
  const int SAFE = PH2 + PH + 1;
  for (int base = blockIdx.x * 256; base < nact; base += 1024 * 256) {
    int i0 = base + wave * 64;
    int pv[4];
    #pragma unroll
    for (int tt = 0; tt < 4; ++tt) {
      int e2 = i0 + tt * 16 + l15;
      if (e2 < nact) {
        int idx = list[e2];
        int z = idx >> 14, y = (idx >> 7) & 127, x = idx & 127;
        pv[tt] = ((z + 1) * PH + (y + 1)) * PH + (x + 1);
      } else pv[tt] = SAFE;
    }
    f32x4 acc[4];
    #pragma unroll
    for (int tt = 0; tt < 4; ++tt) { f32x4 zf = {0.f,0.f,0.f,0.f}; acc[tt] = zf; }
    #pragma unroll
    for (int p = 0; p < 14; ++p) {
      const int t1 = 2 * p, t2 = (2 * p + 1 < 27) ? 2 * p + 1 : 2 * p;
      const int s1 = ((t1 / 9) - 1) * PH2 + (((t1 % 9) / 3) - 1) * PH + ((t1 % 3) - 1);
      const int s2 = ((t2 / 9) - 1) * PH2 + (((t2 % 9) / 3) - 1) * PH + ((t2 % 3) - 1);
      int sh = (quad >= 2) ? s2 : s1;
      bf16x8 b = *(const bf16x8*)&ldsB[(p * 64 + lane) * 8];
      #pragma unroll
      for (int tt = 0; tt < 4; ++tt) {
        bf16x8 a = *(const bf16x8*)(h0p + (size_t)(pv[tt] + sh) * 16 + ((quad & 1) << 3));
        acc[tt] = __builtin_amdgcn_mfma_f32_16x16x32_bf16(a, b, acc[tt], 0, 0, 0);
      }
    }
    float sc = wbuf[OS0B + l15], sb = wbuf[OB0B + l15];
    #pragma unroll
    for (int tt = 0; tt < 4; ++tt)
      #pragma unroll
      for (int r = 0; r < 4; ++r) {
        int e2 = i0 + tt * 16 + quad * 4 + r;
        if (e2 < nact) {
          int idx = list[e2];
          int z = idx >> 14, y = (idx >> 7) & 127, x = idx & 127;
          int pvo = ((z + 1) * PH + (y + 1)) * PH + (x + 1);
          float vv = fmaxf(fmaf(acc[tt][r], sc, sb), 0.f);
          h1p[(size_t)pvo * 16 + l15] = (short)f2bf_bits(vv);
        }
      }
  }
}

// ---- convd0 via MFMA: 16ic -> 32oc, stride 2, tap-pairs K=32 ----
__global__ __launch_bounds__(256) void convd0_mfma_k(
    const short* __restrict__ h1p, const float* __restrict__ m1f,
    const short* __restrict__ WI, const float* __restrict__ wbuf,
    short* __restrict__ Pout)
{
  __shared__ short ldsB[14 * 1024];   // 28 KB
  int tid = threadIdx.x;
  for (int i = tid; i < 14 * 128; i += 256)
    ((uint4*)ldsB)[i] = ((const uint4*)(WI + IWD0))[i];
  __syncthreads();
  int wave = tid >> 6, lane = tid & 63, quad = lane >> 4, l15 = lane & 15;
  int rowid = blockIdx.x * 4 + wave;
  int z = rowid >> 6, y = rowid & 63;
  int base_row = ((2 * z) * PH + 2 * y) * PH;
  f32x4 acc[4][2];
  #pragma unroll
  for (int tt = 0; tt < 4; ++tt)
  #pragma unroll
  for (int h = 0; h < 2; ++h) { f32x4 zf = {0.f,0.f,0.f,0.f}; acc[tt][h] = zf; }
  #pragma unroll
  for (int p = 0; p < 14; ++p) {
    const int t1 = 2 * p, t2 = (2 * p + 1 < 27) ? 2 * p + 1 : 2 * p;
    const int s1 = (t1 / 9) * PH2 + ((t1 % 9) / 3) * PH + (t1 % 3);
    const int s2 = (t2 / 9) * PH2 + ((t2 % 9) / 3) * PH + (t2 % 3);
    int sh = (quad >= 2) ? s2 : s1;
    bf16x8 b0 = *(const bf16x8*)&ldsB[((p * 2 + 0) * 64 + lane) * 8];
    bf16x8 b1 = *(const bf16x8*)&ldsB[((p * 2 + 1) * 64 + lane) * 8];
    bf16x8 a[4];
    #pragma unroll
    for (int tt = 0; tt < 4; ++tt) {
      int vin = base_row + sh + 2 * (tt * 16 + l15);
      a[tt] = *(const bf16x8*)(h1p + (size_t)vin * 16 + ((quad & 1) << 3));
    }
    #pragma unroll
    for (int tt = 0; tt < 4; ++tt) {
      acc[tt][0] = __builtin_amdgcn_mfma_f32_16x16x32_bf16(a[tt], b0, acc[tt][0], 0, 0, 0);
      acc[tt][1] = __builtin_amdgcn_mfma_f32_16x16x32_bf16(a[tt], b1, acc[tt][1], 0, 0, 0);
    }
  }
  float sc[2] = { wbuf[OSD0 + l15], wbuf[OSD0 + 16 + l15] };
  float sb[2] = { wbuf[OBD0 + l15], wbuf[OBD0 + 16 + l15] };
  int mrow = (z * 64 + y) * 64;
  int obase = ((z + 1) * PD + (y + 1)) * PD + 1;
  #pragma unroll
  for (int tt = 0; tt < 4; ++tt) {
    float4 mv = *(const float4*)&m1f[mrow + tt * 16 + quad * 4];
    float mvr[4] = {mv.x, mv.y, mv.z, mv.w};
    #pragma unroll
    for (int h = 0; h < 2; ++h)
      #pragma unroll
      for (int r = 0; r < 4; ++r) {
        float vv = fmaxf(fmaf(acc[tt][h][r], sc[h], sb[h]), 0.f) * mvr[r];
        int vox = obase + tt * 16 + quad * 4 + r;
        Pout[(size_t)vox * 32 + h * 16 + l15] = (short)f2bf_bits(vv);
      }
  }
}

// ---- conv1 via MFMA implicit GEMM: 32->32 ch over padded 66^3 ----
// r6 shape (2 rows/wave, grid 512) + coalesced bf16 image staging.
__global__ __launch_bounds__(256) void conv1_mfma_k(
    const short* __restrict__ Pin, short* __restrict__ Pout,
    const short* __restrict__ WI, const float* __restrict__ wbuf,
    int sof, int bof, const float* __restrict__ m1f)
{
  __shared__ short ldsB[27 * 1024];   // 54 KB
  int tid = threadIdx.x;
  for (int i = tid; i < 27 * 128; i += 256)
    ((uint4*)ldsB)[i] = ((const uint4*)WI)[i];
  __syncthreads();

  int wave = tid >> 6, lane = tid & 63;
  int quad = lane >> 4, l15 = lane & 15;

  f32x4 acc[2][4][2];
  #pragma unroll
  for (int rr = 0; rr < 2; ++rr)
  #pragma unroll
  for (int tt = 0; tt < 4; ++tt)
  #pragma unroll
  for (int h = 0; h < 2; ++h) {
    f32x4 zf = {0.f, 0.f, 0.f, 0.f};
    acc[rr][tt][h] = zf;
  }

  int rowid0 = blockIdx.x * 8 + wave * 2;
  int abase[2], zz[2], yy[2];
  #pragma unroll
  for (int rr = 0; rr < 2; ++rr) {
    int rowid = rowid0 + rr;
    zz[rr] = rowid >> 6; yy[rr] = rowid & 63;
    abase[rr] = ((zz[rr] + 1) * PD + (yy[rr] + 1) ) * PD + 1;
  }

  #pragma unroll 1
  for (int k = 0; k < 27; ++k) {
    int dz = k / 9, r9 = k - dz * 9, dy = r9 / 3, dx = r9 - dy * 3;
    int shift = (dz - 1) * PD2 + (dy - 1) * PD + (dx - 1);
    bf16x8 b0 = *(const bf16x8*)&ldsB[((k * 2 + 0) * 64 + lane) * 8];
    bf16x8 b1 = *(const bf16x8*)&ldsB[((k * 2 + 1) * 64 + lane) * 8];
    bf16x8 a[2][4];
    #pragma unroll
    for (int rr = 0; rr < 2; ++rr)
    #pragma unroll
    for (int tt = 0; tt < 4; ++tt) {
      int off = (abase[rr] + shift + tt * 16 + l15) * 32 + quad * 8;
      a[rr][tt] = *(const bf16x8*)(Pin + off);
    }
    #pragma unroll
    for (int rr = 0; rr < 2; ++rr)
    #pragma unroll
    for (int tt = 0; tt < 4; ++tt) {
      acc[rr][tt][0] = __builtin_amdgcn_mfma_f32_16x16x32_bf16(a[rr][tt], b0, acc[rr][tt][0], 0, 0, 0);
      acc[rr][tt][1] = __builtin_amdgcn_mfma_f32_16x16x32_bf16(a[rr][tt], b1, acc[rr][tt][1], 0, 0, 0);
    }
  }

  float sc[2] = { wbuf[sof + l15], wbuf[sof + 16 + l15] };
  float sh[2] = { wbuf[bof + l15], wbuf[bof + 16 + l15] };

  #pragma unroll
  for (int rr = 0; rr < 2; ++rr) {
    int mrow = (zz[rr] * 64 + yy[rr]) * 64;
    #pragma unroll
    for (int tt = 0; tt < 4; ++tt) {
      const float4 mv = *(const float4*)&m1f[mrow + tt * 16 + quad * 4];
      float mvr[4] = {mv.x, mv.y, mv.z, mv.w};
      #pragma unroll
      for (int h = 0; h < 2; ++h) {
        #pragma unroll
        for (int r = 0; r < 4; ++r) {
          float v = fmaxf(fmaf(acc[rr][tt][h][r], sc[h], sh[h]), 0.f) * mvr[r];
          int vox = abase[rr] + tt * 16 + quad * 4 + r;
          Pout[vox * 32 + h * 16 + l15] = (short)f2bf_bits(v);
        }
      }
    }
  }
}

// ---- trilinear sample from padded channel-last bf16 volume ----
__global__ __launch_bounds__(256) void sample_k(
    const void* __restrict__ coords, const int* __restrict__ flag,
    const short* __restrict__ vol, void* __restrict__ out)
{
  int p = blockIdx.x * 256 + threadIdx.x;
  if (p >= NPTS) return;
  int bf = *flag;
  float cx = ldIn(coords, 3l * p + 0, bf);
  float cy = ldIn(coords, 3l * p + 1, bf);
  float cz = ldIn(coords, 3l * p + 2, bf);
  float fx = (cx + 1.f) * 0.5f * 63.f;
  float fy = (cy + 1.f) * 0.5f * 63.f;
  float fz = (cz + 1.f) * 0.5f * 63.f;
  float x0f = floorf(fx), y0f = floorf(fy), z0f = floorf(fz);
  int x0 = (int)x0f, y0 = (int)y0f, z0 = (int)z0f;
  float tx = fx - x0f, ty = fy - y0f, tz = fz - z0f;
  int li[8]; float wt[8];
  #pragma unroll
  for (int dz = 0; dz < 2; ++dz)
  #pragma unroll
  for (int dy = 0; dy < 2; ++dy)
  #pragma unroll
  for (int dx = 0; dx < 2; ++dx) {
    int t = dz * 4 + dy * 2 + dx;
    int xi = x0 + dx, yi = y0 + dy, zi = z0 + dz;
    bool ok = (unsigned)xi < 64u && (unsigned)yi < 64u && (unsigned)zi < 64u;
    int xc = min(max(xi, 0), 63), yc = min(max(yi, 0), 63), zc = min(max(zi, 0), 63);
    li[t] = ((zc + 1) * PD + (yc + 1)) * PD + (xc + 1);
    float w = (dx ? tx : 1.f - tx) * (dy ? ty : 1.f - ty) * (dz ? tz : 1.f - tz);
    wt[t] = ok ? w : 0.f;
  }
  #pragma unroll
  for (int cc = 0; cc < 4; ++cc) {
    float s[8];
    #pragma unroll
    for (int j = 0; j < 8; ++j) s[j] = 0.f;
    #pragma unroll
    for (int t = 0; t < 8; ++t) {
      bf16x8 v = *(const bf16x8*)(vol + (size_t)li[t] * 32 + cc * 8);
      #pragma unroll
      for (int j = 0; j < 8; ++j) s[j] += bfbits2f(v[j]) * wt[t];
    }
    if (bf) {
      union { unsigned short us[8]; uint4 v; } u;
      #pragma unroll
      for (int j = 0; j < 8; ++j) u.us[j] = f2bf_bits(s[j]);
      ((uint4*)out)[p * 4 + cc] = u.v;
    } else {
      #pragma unroll
      for (int j = 0; j < 8; ++j) ((float*)out)[(size_t)p * 32 + cc * 8 + j] = s[j];
    }
  }
}

extern "C" void kernel_launch(void* const* d_in, const int* in_sizes, int n_in,
                              void* d_out, int out_size, void* d_ws, size_t ws_size,
                              hipStream_t stream)
{
  const void* xf     = d_in[0];
  const int*  mask   = (const int*)d_in[1];
  const void* coords = d_in[2];
  const void* w0a = d_in[3];
  const void* s0a = d_in[4];
  const void* b0a = d_in[5];
  const void* w0b = d_in[6];
  const void* s0b = d_in[7];
  const void* b0b = d_in[8];
  const void* wd0 = d_in[9];
  const void* sd0 = d_in[10];
  const void* bd0 = d_in[11];
  const void* w1a = d_in[12];
  const void* s1a = d_in[13];
  const void* b1a = d_in[14];
  const void* w1b = d_in[15];
  const void* s1b = d_in[16];
  const void* b1b = d_in[17];

  char* ws = (char*)d_ws;
  size_t cur = 0;
  auto alloc = [&](size_t bytes) -> size_t {
    size_t o = cur; cur = (cur + bytes + 255) & ~(size_t)255; return o;
  };
  size_t o_flag = alloc(4);
  size_t o_cnt  = alloc(4);
  size_t o_m1f  = alloc((size_t)M3 * 4);
  size_t o_wbuf = alloc((size_t)WTOT * 4);
  size_t o_WI   = alloc((size_t)ITOT * 2);
  size_t o_list = alloc((size_t)N3 * 4);
  size_t o_h0p  = alloc((size_t)PH3 * 16 * 2);    // 70 MB
  size_t o_h1p  = alloc((size_t)PH3 * 16 * 2);    // 70 MB
  size_t o_P1   = alloc((size_t)PVOX * 32 * 2);   // 18.4 MB
  size_t o_P2   = alloc((size_t)PVOX * 32 * 2);   // 18.4 MB (xq aliases its head)

  int*   flag = (int*)(ws + o_flag);
  int*   cnt  = (int*)(ws + o_cnt);
  float* m1f  = (float*)(ws + o_m1f);
  float* wbuf = (float*)(ws + o_wbuf);
  short* WI   = (short*)(ws + o_WI);
  int*   list = (int*)(ws + o_list);
  short* h0p  = (short*)(ws + o_h0p);
  short* h1p  = (short*)(ws + o_h1p);
  short* P1   = (short*)(ws + o_P1);
  short* P2   = (short*)(ws + o_P2);
  short* xq   = (short*)(ws + o_P2);              // alias: xq (17.6 MB) in P2 region

  hipMemsetAsync(cnt, 0, 4, stream);
  // zero h0p + h1p + P1 + P2 (incl. xq halo) in one contiguous sweep (~177 MB)
  hipMemsetAsync(ws + o_h0p, 0,
                 (o_P2 - o_h0p) + (size_t)PVOX * 32 * 2, stream);

  probe_k<<<1, 64, 0, stream>>>((const unsigned*)s0a, flag);
  cvt_k<<<(WTOT + 255) / 256, 256, 0, stream>>>(w0a, w0b, wd0, w1a, w1b,
                                                s0a, b0a, s0b, b0b, sd0, bd0,
                                                s1a, b1a, s1b, b1b, flag, wbuf);
  wtrans_k<<<108, 256, 0, stream>>>(wbuf, WI);
  masklist_k<<<256, 256, 0, stream>>>(mask, list, cnt);
  dsmask_k<<<M3 / 256, 256, 0, stream>>>(mask, m1f);

  pack_k<<<N3 / 256, 256, 0, stream>>>(xf, flag, mask, xq);
  conv0a_mfma_k<<<1024, 256, 0, stream>>>(xq, list, cnt, WI, wbuf, h0p);
  // xq dead; wipe P2 region (stale xq bytes would leak into P2's halo otherwise)
  hipMemsetAsync(ws + o_P2, 0, (size_t)PVOX * 32 * 2, stream);
  conv0b_mfma_k<<<1024, 256, 0, stream>>>(h0p, list, cnt, WI, wbuf, h1p);
  convd0_mfma_k<<<1024, 256, 0, stream>>>(h1p, m1f, WI, wbuf, P1);

  conv1_mfma_k<<<512, 256, 0, stream>>>(P1, P2, WI + IW1A, wbuf, OS1A, OB1A, m1f);
  conv1_mfma_k<<<512, 256, 0, stream>>>(P2, P1, WI + IW1B, wbuf, OS1B, OB1B, m1f);

  sample_k<<<NPTS / 256, 256, 0, stream>>>(coords, flag, P1, d_out);
}

// Round 11
// 307.167 us; speedup vs baseline: 1.9112x; 1.1989x over previous
//
#include <hip/hip_runtime.h>
#include <hip/hip_bf16.h>

#define N   128
#define N3  (N*N*N)
#define M   64
#define M3  (M*M*M)
#define NPTS 65536
#define PD  66
#define PD2 (PD*PD)
#define PVOX (PD*PD*PD)
#define PH  130
#define PH2 (PH*PH)
#define PH3 (PH*PH*PH)
#define CAP   393216          // compact-slot capacity (~1.9x expected 210k actives)
#define ZSLOT (CAP - 1)       // zeroed sentinel slot for inactive/OOB taps

// float offsets inside the converted-weights buffer
enum : int {
  OW0A = 0,                 // 16*3*27   = 1296
  OW0B = 1296,              // 16*16*27  = 6912
  OWD0 = 8208,              // 32*16*27  = 13824
  OW1A = 22032,             // 32*32*27  = 27648
  OW1B = 49680,             // 32*32*27  = 27648
  OS0A = 77328, OB0A = 77344,
  OS0B = 77360, OB0B = 77376,
  OSD0 = 77392, OBD0 = 77424,
  OS1A = 77456, OB1A = 77488,
  OS1B = 77520, OB1B = 77552,
  WTOT = 77584
};

// short offsets inside the bf16 LDS-image buffer
enum : int {
  IW0A = 0,       // 4*512   = 2048
  IW0B = 2048,    // 14*512  = 7168
  IWD0 = 9216,    // 14*1024 = 14336
  IW1A = 23552,   // 27*1024 = 27648
  IW1B = 51200,   // 27*1024 = 27648
  ITOT = 78848
};

typedef short bf16x8 __attribute__((ext_vector_type(8)));
typedef float f32x4  __attribute__((ext_vector_type(4)));

__device__ __forceinline__ unsigned short f2bf_bits(float f) {
  __hip_bfloat16 b = __float2bfloat16(f);
  union { __hip_bfloat16 b; unsigned short u; } cv; cv.b = b; return cv.u;
}
__device__ __forceinline__ float bfbits2f(short s) {
  union { unsigned u; float f; } c; c.u = ((unsigned)(unsigned short)s) << 16; return c.f;
}

__device__ __forceinline__ float ldIn(const void* p, long i, int bf) {
  return bf ? __bfloat162float(((const __hip_bfloat16*)p)[i]) : ((const float*)p)[i];
}

// ---- dtype probe ----
__global__ void probe_k(const unsigned* __restrict__ s0a_raw, int* __restrict__ flag) {
  if (threadIdx.x == 0 && blockIdx.x == 0) {
    int all = 1;
    for (int i = 0; i < 8; ++i) {
      unsigned w = s0a_raw[i];
      if (((w >> 8) & 0xFFu) != 0x3Fu) all = 0;
    }
    *flag = all;
  }
}

// ---- convert all weights/scales/shifts to one fp32 buffer ----
__global__ __launch_bounds__(256) void cvt_k(
    const void* w0a, const void* w0b, const void* wd0,
    const void* w1a, const void* w1b,
    const void* s0a, const void* b0a,
    const void* s0b, const void* b0b,
    const void* sd0, const void* bd0,
    const void* s1a, const void* b1a,
    const void* s1b, const void* b1b,
    const int* __restrict__ flag, float* __restrict__ wbuf)
{
  int i = blockIdx.x * 256 + threadIdx.x;
  if (i >= WTOT) return;
  int bf = *flag;
  const void* src; int off;
  if      (i < OW0B) { src = w0a; off = OW0A; }
  else if (i < OWD0) { src = w0b; off = OW0B; }
  else if (i < OW1A) { src = wd0; off = OWD0; }
  else if (i < OW1B) { src = w1a; off = OW1A; }
  else if (i < OS0A) { src = w1b; off = OW1B; }
  else if (i < OB0A) { src = s0a; off = OS0A; }
  else if (i < OS0B) { src = b0a; off = OB0A; }
  else if (i < OB0B) { src = s0b; off = OS0B; }
  else if (i < OSD0) { src = b0b; off = OB0B; }
  else if (i < OBD0) { src = sd0; off = OSD0; }
  else if (i < OS1A) { src = bd0; off = OBD0; }
  else if (i < OB1A) { src = s1a; off = OS1A; }
  else if (i < OS1B) { src = b1a; off = OB1A; }
  else if (i < OB1B) { src = s1b; off = OS1B; }
  else               { src = b1b; off = OB1B; }
  wbuf[i] = ldIn(src, i - off, bf);
}

// ---- build bf16 LDS images (exact per-kernel staging byte layout) ----
__global__ __launch_bounds__(256) void wtrans_k(const float* __restrict__ wbuf,
                                               short* __restrict__ WI)
{
  int i = blockIdx.x * 256 + threadIdx.x;
  if (i >= 27648) return;
  if (i < 2048) {
    int kb = i >> 9, l = (i >> 3) & 63, j = i & 7;
    int k = ((l >> 4) << 3) + j;
    int tap = kb * 8 + (k >> 2), ch = k & 3, oc = l & 15;
    float v = (tap < 27 && ch < 3) ? wbuf[OW0A + (oc * 3 + ch) * 27 + tap] : 0.f;
    WI[IW0A + i] = (short)f2bf_bits(v);
  }
  if (i < 7168) {
    int p = i >> 9, l = (i >> 3) & 63, j = i & 7;
    int kg = ((l >> 4) << 3) + j;
    int tap = 2 * p + (kg >> 4);
    int ic = kg & 15, oc = l & 15;
    float v = (tap < 27) ? wbuf[OW0B + (oc * 16 + ic) * 27 + tap] : 0.f;
    WI[IW0B + i] = (short)f2bf_bits(v);
  }
  if (i < 14336) {
    int p = i >> 10, h = (i >> 9) & 1, l = (i >> 3) & 63, j = i & 7;
    int kg = ((l >> 4) << 3) + j;
    int tap = 2 * p + (kg >> 4);
    int ic = kg & 15;
    int oc = (h << 4) + (l & 15);
    float v = (tap < 27) ? wbuf[OWD0 + (oc * 16 + ic) * 27 + tap] : 0.f;
    WI[IWD0 + i] = (short)f2bf_bits(v);
  }
  {
    int t = i >> 10, h = (i >> 9) & 1, l = (i >> 3) & 63, j = i & 7;
    int ic = ((l >> 4) << 3) + j;
    int oc = (h << 4) + (l & 15);
    WI[IW1A + i] = (short)f2bf_bits(wbuf[OW1A + (oc * 32 + ic) * 27 + t]);
    WI[IW1B + i] = (short)f2bf_bits(wbuf[OW1B + (oc * 32 + ic) * 27 + t]);
  }
}

// ---- active-voxel list + padded slot-index volume ----
__global__ __launch_bounds__(256) void masklist_k(const int* __restrict__ mask,
                                                  int* __restrict__ list,
                                                  int* __restrict__ idxvol,
                                                  int* __restrict__ cnt)
{
  __shared__ int lpos, lbase;
  int t = threadIdx.x;
  int start = blockIdx.x * 8192;
  if (t == 0) lpos = 0;
  __syncthreads();
  int myc = 0;
  #pragma unroll 4
  for (int i = 0; i < 32; ++i) myc += (mask[start + i * 256 + t] != 0);
  atomicAdd(&lpos, myc);
  __syncthreads();
  if (t == 0) { lbase = atomicAdd(cnt, lpos); lpos = 0; }
  __syncthreads();
  #pragma unroll 4
  for (int i = 0; i < 32; ++i) {
    int idx = start + i * 256 + t;
    if (mask[idx]) {
      int p = atomicAdd(&lpos, 1);
      int slot = lbase + p;
      if (slot < ZSLOT) {
        list[slot] = idx;
        int z = idx >> 14, y = (idx >> 7) & 127, x = idx & 127;
        idxvol[((z + 1) * PH + (y + 1)) * PH + (x + 1)] = slot;
      }
    }
  }
}

// ---- m1f = float(maxpool3d(mask, 3, stride 2, pad 1)) ----
__global__ __launch_bounds__(256) void dsmask_k(const int* __restrict__ mask,
                                                float* __restrict__ m1f)
{
  int idx = blockIdx.x * 256 + threadIdx.x;
  if (idx >= M3) return;
  int z = idx >> 12, y = (idx >> 6) & 63, x = idx & 63;
  int r = 0;
  #pragma unroll
  for (int dz = 0; dz < 3; ++dz) {
    int iz = 2 * z + dz - 1;
    if ((unsigned)iz >= 128u) continue;
    #pragma unroll
    for (int dy = 0; dy < 3; ++dy) {
      int iy = 2 * y + dy - 1;
      if ((unsigned)iy >= 128u) continue;
      #pragma unroll
      for (int dx = 0; dx < 3; ++dx) {
        int ix = 2 * x + dx - 1;
        if ((unsigned)ix >= 128u) continue;
        r |= mask[(iz << 14) | (iy << 7) | ix];
      }
    }
  }
  m1f[idx] = r ? 1.f : 0.f;
}

// ---- pack x_feat (active voxels only) into compact 4ch bf16 slots ----
__global__ __launch_bounds__(256) void pack_c_k(const void* __restrict__ xf,
                                                const int* __restrict__ flag,
                                                const int* __restrict__ list,
                                                const int* __restrict__ cnt,
                                                short* __restrict__ xc)
{
  int nact = *cnt;
  int bf = *flag;
  for (int i = blockIdx.x * 256 + threadIdx.x; i < nact; i += 1024 * 256) {
    int idx = list[i];
    union { unsigned short us[4]; uint2 v; } u;
    u.us[0] = f2bf_bits(ldIn(xf, idx, bf));
    u.us[1] = f2bf_bits(ldIn(xf, (long)N3 + idx, bf));
    u.us[2] = f2bf_bits(ldIn(xf, 2l * N3 + idx, bf));
    u.us[3] = 0;
    *(uint2*)(xc + (size_t)i * 4) = u.v;
  }
}

__device__ __forceinline__ int tap_shift_PH(int t) {
  if (t >= 27) return 0;
  int dz = t / 9, r9 = t - dz * 9, dy = r9 / 3, dx = r9 - dy * 3;
  return (dz - 1) * PH2 + (dy - 1) * PH + (dx - 1);
}
__device__ __forceinline__ int slot_of(const int* __restrict__ idxvol, int nb) {
  int s = idxvol[nb];
  return s < 0 ? ZSLOT : s;
}

// ---- conv0a via MFMA over the active list: K = 28 taps x 4ch = 4 k-blocks ----
__global__ __launch_bounds__(256) void conv0a_mfma_k(
    const short* __restrict__ xc, const int* __restrict__ idxvol,
    const int* __restrict__ list, const int* __restrict__ cnt,
    const short* __restrict__ WI, const float* __restrict__ wbuf,
    short* __restrict__ h0c)
{
  __shared__ short ldsB[4 * 512];   // 4 KB
  int tid = threadIdx.x;
  if (tid < 256) ((uint4*)ldsB)[tid] = ((const uint4*)(WI + IW0A))[tid];
  __syncthreads();
  int nact = *cnt;
  int wave = tid >> 6, lane = tid & 63, quad = lane >> 4, l15 = lane & 15;
  const int SAFE = PH2 + PH + 1;
  for (int base = blockIdx.x * 256; base < nact; base += 1024 * 256) {
    int i0 = base + wave * 64;
    int pv[4];
    #pragma unroll
    for (int tt = 0; tt < 4; ++tt) {
      int e2 = i0 + tt * 16 + l15;
      if (e2 < nact) {
        int idx = list[e2];
        int z = idx >> 14, y = (idx >> 7) & 127, x = idx & 127;
        pv[tt] = ((z + 1) * PH + (y + 1)) * PH + (x + 1);
      } else pv[tt] = SAFE;
    }
    f32x4 acc[4];
    #pragma unroll
    for (int tt = 0; tt < 4; ++tt) { f32x4 zf = {0.f,0.f,0.f,0.f}; acc[tt] = zf; }
    #pragma unroll
    for (int kb = 0; kb < 4; ++kb) {
      int t0 = kb * 8 + quad * 2, t1 = t0 + 1;
      int s0 = tap_shift_PH(t0), s1 = tap_shift_PH(t1);
      bf16x8 b = *(const bf16x8*)&ldsB[(kb * 64 + lane) * 8];
      #pragma unroll
      for (int tt = 0; tt < 4; ++tt) {
        int sa = slot_of(idxvol, pv[tt] + s0);
        int sb2 = slot_of(idxvol, pv[tt] + s1);
        union { struct { uint2 lo, hi; } p; bf16x8 v; } cv;
        cv.p.lo = *(const uint2*)(xc + (size_t)sa * 4);
        cv.p.hi = *(const uint2*)(xc + (size_t)sb2 * 4);
        acc[tt] = __builtin_amdgcn_mfma_f32_16x16x32_bf16(cv.v, b, acc[tt], 0, 0, 0);
      }
    }
    float sc = wbuf[OS0A + l15], sb = wbuf[OB0A + l15];
    #pragma unroll
    for (int tt = 0; tt < 4; ++tt)
      #pragma unroll
      for (int r = 0; r < 4; ++r) {
        int e2 = i0 + tt * 16 + quad * 4 + r;
        if (e2 < nact) {
          float vv = fmaxf(fmaf(acc[tt][r], sc, sb), 0.f);
          h0c[(size_t)e2 * 16 + l15] = (short)f2bf_bits(vv);
        }
      }
  }
}

// ---- conv0b via MFMA over the active list: 16ic -> 16oc, tap-pairs K=32 ----
__global__ __launch_bounds__(256) void conv0b_mfma_k(
    const short* __restrict__ h0c, const int* __restrict__ idxvol,
    const int* __restrict__ list, const int* __restrict__ cnt,
    const short* __restrict__ WI, const float* __restrict__ wbuf,
    short* __restrict__ h1c)
{
  __shared__ short ldsB[14 * 512];   // 14 KB
  int tid = threadIdx.x;
  for (int i = tid; i < 14 * 64; i += 256)
    ((uint4*)ldsB)[i] = ((const uint4*)(WI + IW0B))[i];
  __syncthreads();
  int nact = *cnt;
  int wave = tid >> 6, lane = tid & 63, quad = lane >> 4, l15 = lane & 15;
  const int SAFE = PH2 + PH + 1;
  for (int base = blockIdx.x * 256; base < nact; base += 1024 * 256) {
    int i0 = base + wave * 64;
    int pv[4];
    #pragma unroll
    for (int tt = 0; tt < 4; ++tt) {
      int e2 = i0 + tt * 16 + l15;
      if (e2 < nact) {
        int idx = list[e2];
        int z = idx >> 14, y = (idx >> 7) & 127, x = idx & 127;
        pv[tt] = ((z + 1) * PH + (y + 1)) * PH + (x + 1);
      } else pv[tt] = SAFE;
    }
    f32x4 acc[4];
    #pragma unroll
    for (int tt = 0; tt < 4; ++tt) { f32x4 zf = {0.f,0.f,0.f,0.f}; acc[tt] = zf; }
    #pragma unroll
    for (int p = 0; p < 14; ++p) {
      const int t1 = 2 * p, t2 = (2 * p + 1 < 27) ? 2 * p + 1 : 2 * p;
      const int s1 = ((t1 / 9) - 1) * PH2 + (((t1 % 9) / 3) - 1) * PH + ((t1 % 3) - 1);
      const int s2 = ((t2 / 9) - 1) * PH2 + (((t2 % 9) / 3) - 1) * PH + ((t2 % 3) - 1);
      int sh = (quad >= 2) ? s2 : s1;
      bf16x8 b = *(const bf16x8*)&ldsB[(p * 64 + lane) * 8];
      #pragma unroll
      for (int tt = 0; tt < 4; ++tt) {
        int ss = slot_of(idxvol, pv[tt] + sh);
        bf16x8 a = *(const bf16x8*)(h0c + (size_t)ss * 16 + ((quad & 1) << 3));
        acc[tt] = __builtin_amdgcn_mfma_f32_16x16x32_bf16(a, b, acc[tt], 0, 0, 0);
      }
    }
    float sc = wbuf[OS0B + l15], sb = wbuf[OB0B + l15];
    #pragma unroll
    for (int tt = 0; tt < 4; ++tt)
      #pragma unroll
      for (int r = 0; r < 4; ++r) {
        int e2 = i0 + tt * 16 + quad * 4 + r;
        if (e2 < nact) {
          float vv = fmaxf(fmaf(acc[tt][r], sc, sb), 0.f);
          h1c[(size_t)e2 * 16 + l15] = (short)f2bf_bits(vv);
        }
      }
  }
}

// ---- convd0 via MFMA: 16ic -> 32oc, stride 2, tap-pairs K=32 ----
__global__ __launch_bounds__(256) void convd0_mfma_k(
    const short* __restrict__ h1c, const int* __restrict__ idxvol,
    const float* __restrict__ m1f,
    const short* __restrict__ WI, const float* __restrict__ wbuf,
    short* __restrict__ Pout)
{
  __shared__ short ldsB[14 * 1024];   // 28 KB
  int tid = threadIdx.x;
  for (int i = tid; i < 14 * 128; i += 256)
    ((uint4*)ldsB)[i] = ((const uint4*)(WI + IWD0))[i];
  __syncthreads();
  int wave = tid >> 6, lane = tid & 63, quad = lane >> 4, l15 = lane & 15;
  int rowid = blockIdx.x * 4 + wave;
  int z = rowid >> 6, y = rowid & 63;
  int base_row = ((2 * z) * PH + 2 * y) * PH;
  f32x4 acc[4][2];
  #pragma unroll
  for (int tt = 0; tt < 4; ++tt)
  #pragma unroll
  for (int h = 0; h < 2; ++h) { f32x4 zf = {0.f,0.f,0.f,0.f}; acc[tt][h] = zf; }
  #pragma unroll
  for (int p = 0; p < 14; ++p) {
    const int t1 = 2 * p, t2 = (2 * p + 1 < 27) ? 2 * p + 1 : 2 * p;
    const int s1 = (t1 / 9) * PH2 + ((t1 % 9) / 3) * PH + (t1 % 3);
    const int s2 = (t2 / 9) * PH2 + ((t2 % 9) / 3) * PH + (t2 % 3);
    int sh = (quad >= 2) ? s2 : s1;
    bf16x8 b0 = *(const bf16x8*)&ldsB[((p * 2 + 0) * 64 + lane) * 8];
    bf16x8 b1 = *(const bf16x8*)&ldsB[((p * 2 + 1) * 64 + lane) * 8];
    bf16x8 a[4];
    #pragma unroll
    for (int tt = 0; tt < 4; ++tt) {
      int vin = base_row + sh + 2 * (tt * 16 + l15);
      int ss = slot_of(idxvol, vin);
      a[tt] = *(const bf16x8*)(h1c + (size_t)ss * 16 + ((quad & 1) << 3));
    }
    #pragma unroll
    for (int tt = 0; tt < 4; ++tt) {
      acc[tt][0] = __builtin_amdgcn_mfma_f32_16x16x32_bf16(a[tt], b0, acc[tt][0], 0, 0, 0);
      acc[tt][1] = __builtin_amdgcn_mfma_f32_16x16x32_bf16(a[tt], b1, acc[tt][1], 0, 0, 0);
    }
  }
  float sc[2] = { wbuf[OSD0 + l15], wbuf[OSD0 + 16 + l15] };
  float sb[2] = { wbuf[OBD0 + l15], wbuf[OBD0 + 16 + l15] };
  int mrow = (z * 64 + y) * 64;
  int obase = ((z + 1) * PD + (y + 1)) * PD + 1;
  #pragma unroll
  for (int tt = 0; tt < 4; ++tt) {
    float4 mv = *(const float4*)&m1f[mrow + tt * 16 + quad * 4];
    float mvr[4] = {mv.x, mv.y, mv.z, mv.w};
    #pragma unroll
    for (int h = 0; h < 2; ++h)
      #pragma unroll
      for (int r = 0; r < 4; ++r) {
        float vv = fmaxf(fmaf(acc[tt][h][r], sc[h], sb[h]), 0.f) * mvr[r];
        int vox = obase + tt * 16 + quad * 4 + r;
        Pout[(size_t)vox * 32 + h * 16 + l15] = (short)f2bf_bits(vv);
      }
  }
}

// ---- conv1 via MFMA implicit GEMM: 32->32 ch over padded 66^3 ----
__global__ __launch_bounds__(256) void conv1_mfma_k(
    const short* __restrict__ Pin, short* __restrict__ Pout,
    const short* __restrict__ WI, const float* __restrict__ wbuf,
    int sof, int bof, const float* __restrict__ m1f)
{
  __shared__ short ldsB[27 * 1024];   // 54 KB
  int tid = threadIdx.x;
  for (int i = tid; i < 27 * 128; i += 256)
    ((uint4*)ldsB)[i] = ((const uint4*)WI)[i];
  __syncthreads();

  int wave = tid >> 6, lane = tid & 63;
  int quad = lane >> 4, l15 = lane & 15;

  f32x4 acc[2][4][2];
  #pragma unroll
  for (int rr = 0; rr < 2; ++rr)
  #pragma unroll
  for (int tt = 0; tt < 4; ++tt)
  #pragma unroll
  for (int h = 0; h < 2; ++h) {
    f32x4 zf = {0.f, 0.f, 0.f, 0.f};
    acc[rr][tt][h] = zf;
  }

  int rowid0 = blockIdx.x * 8 + wave * 2;
  int abase[2], zz[2], yy[2];
  #pragma unroll
  for (int rr = 0; rr < 2; ++rr) {
    int rowid = rowid0 + rr;
    zz[rr] = rowid >> 6; yy[rr] = rowid & 63;
    abase[rr] = ((zz[rr] + 1) * PD + (yy[rr] + 1)) * PD + 1;
  }

  #pragma unroll 1
  for (int k = 0; k < 27; ++k) {
    int dz = k / 9, r9 = k - dz * 9, dy = r9 / 3, dx = r9 - dy * 3;
    int shift = (dz - 1) * PD2 + (dy - 1) * PD + (dx - 1);
    bf16x8 b0 = *(const bf16x8*)&ldsB[((k * 2 + 0) * 64 + lane) * 8];
    bf16x8 b1 = *(const bf16x8*)&ldsB[((k * 2 + 1) * 64 + lane) * 8];
    bf16x8 a[2][4];
    #pragma unroll
    for (int rr = 0; rr < 2; ++rr)
    #pragma unroll
    for (int tt = 0; tt < 4; ++tt) {
      int off = (abase[rr] + shift + tt * 16 + l15) * 32 + quad * 8;
      a[rr][tt] = *(const bf16x8*)(Pin + off);
    }
    #pragma unroll
    for (int rr = 0; rr < 2; ++rr)
    #pragma unroll
    for (int tt = 0; tt < 4; ++tt) {
      acc[rr][tt][0] = __builtin_amdgcn_mfma_f32_16x16x32_bf16(a[rr][tt], b0, acc[rr][tt][0], 0, 0, 0);
      acc[rr][tt][1] = __builtin_amdgcn_mfma_f32_16x16x32_bf16(a[rr][tt], b1, acc[rr][tt][1], 0, 0, 0);
    }
  }

  float sc[2] = { wbuf[sof + l15], wbuf[sof + 16 + l15] };
  float sh[2] = { wbuf[bof + l15], wbuf[bof + 16 + l15] };

  #pragma unroll
  for (int rr = 0; rr < 2; ++rr) {
    int mrow = (zz[rr] * 64 + yy[rr]) * 64;
    #pragma unroll
    for (int tt = 0; tt < 4; ++tt) {
      const float4 mv = *(const float4*)&m1f[mrow + tt * 16 + quad * 4];
      float mvr[4] = {mv.x, mv.y, mv.z, mv.w};
      #pragma unroll
      for (int h = 0; h < 2; ++h) {
        #pragma unroll
        for (int r = 0; r < 4; ++r) {
          float v = fmaxf(fmaf(acc[rr][tt][h][r], sc[h], sh[h]), 0.f) * mvr[r];
          int vox = abase[rr] + tt * 16 + quad * 4 + r;
          Pout[vox * 32 + h * 16 + l15] = (short)f2bf_bits(v);
        }
      }
    }
  }
}

// ---- trilinear sample from padded channel-last bf16 volume ----
__global__ __launch_bounds__(256) void sample_k(
    const void* __restrict__ coords, const int* __restrict__ flag,
    const short* __restrict__ vol, void* __restrict__ out)
{
  int p = blockIdx.x * 256 + threadIdx.x;
  if (p >= NPTS) return;
  int bf = *flag;
  float cx = ldIn(coords, 3l * p + 0, bf);
  float cy = ldIn(coords, 3l * p + 1, bf);
  float cz = ldIn(coords, 3l * p + 2, bf);
  float fx = (cx + 1.f) * 0.5f * 63.f;
  float fy = (cy + 1.f) * 0.5f * 63.f;
  float fz = (cz + 1.f) * 0.5f * 63.f;
  float x0f = floorf(fx), y0f = floorf(fy), z0f = floorf(fz);
  int x0 = (int)x0f, y0 = (int)y0f, z0 = (int)z0f;
  float tx = fx - x0f, ty = fy - y0f, tz = fz - z0f;
  int li[8]; float wt[8];
  #pragma unroll
  for (int dz = 0; dz < 2; ++dz)
  #pragma unroll
  for (int dy = 0; dy < 2; ++dy)
  #pragma unroll
  for (int dx = 0; dx < 2; ++dx) {
    int t = dz * 4 + dy * 2 + dx;
    int xi = x0 + dx, yi = y0 + dy, zi = z0 + dz;
    bool ok = (unsigned)xi < 64u && (unsigned)yi < 64u && (unsigned)zi < 64u;
    int xc = min(max(xi, 0), 63), yc = min(max(yi, 0), 63), zc = min(max(zi, 0), 63);
    li[t] = ((zc + 1) * PD + (yc + 1)) * PD + (xc + 1);
    float w = (dx ? tx : 1.f - tx) * (dy ? ty : 1.f - ty) * (dz ? tz : 1.f - tz);
    wt[t] = ok ? w : 0.f;
  }
  #pragma unroll
  for (int cc = 0; cc < 4; ++cc) {
    float s[8];
    #pragma unroll
    for (int j = 0; j < 8; ++j) s[j] = 0.f;
    #pragma unroll
    for (int t = 0; t < 8; ++t) {
      bf16x8 v = *(const bf16x8*)(vol + (size_t)li[t] * 32 + cc * 8);
      #pragma unroll
      for (int j = 0; j < 8; ++j) s[j] += bfbits2f(v[j]) * wt[t];
    }
    if (bf) {
      union { unsigned short us[8]; uint4 v; } u;
      #pragma unroll
      for (int j = 0; j < 8; ++j) u.us[j] = f2bf_bits(s[j]);
      ((uint4*)out)[p * 4 + cc] = u.v;
    } else {
      #pragma unroll
      for (int j = 0; j < 8; ++j) ((float*)out)[(size_t)p * 32 + cc * 8 + j] = s[j];
    }
  }
}

extern "C" void kernel_launch(void* const* d_in, const int* in_sizes, int n_in,
                              void* d_out, int out_size, void* d_ws, size_t ws_size,
                              hipStream_t stream)
{
  const void* xf     = d_in[0];
  const int*  mask   = (const int*)d_in[1];
  const void* coords = d_in[2];
  const void* w0a = d_in[3];
  const void* s0a = d_in[4];
  const void* b0a = d_in[5];
  const void* w0b = d_in[6];
  const void* s0b = d_in[7];
  const void* b0b = d_in[8];
  const void* wd0 = d_in[9];
  const void* sd0 = d_in[10];
  const void* bd0 = d_in[11];
  const void* w1a = d_in[12];
  const void* s1a = d_in[13];
  const void* b1a = d_in[14];
  const void* w1b = d_in[15];
  const void* s1b = d_in[16];
  const void* b1b = d_in[17];

  char* ws = (char*)d_ws;
  size_t cur = 0;
  auto alloc = [&](size_t bytes) -> size_t {
    size_t o = cur; cur = (cur + bytes + 255) & ~(size_t)255; return o;
  };
  size_t o_flag = alloc(4);
  size_t o_cnt  = alloc(4);
  size_t o_m1f  = alloc((size_t)M3 * 4);
  size_t o_wbuf = alloc((size_t)WTOT * 4);
  size_t o_WI   = alloc((size_t)ITOT * 2);
  size_t o_list = alloc((size_t)CAP * 4);
  size_t o_idx  = alloc((size_t)PH3 * 4);         // 8.8 MB, memset 0xFF
  size_t o_xc   = alloc((size_t)CAP * 4 * 2);     // 3.1 MB  (zeroed sweep start)
  size_t o_h0c  = alloc((size_t)CAP * 16 * 2);    // 12.6 MB (zeroed)
  size_t o_h1c  = alloc((size_t)CAP * 16 * 2);    // 12.6 MB (zeroed)
  size_t o_P1   = alloc((size_t)PVOX * 32 * 2);   // 18.4 MB (zeroed)
  size_t o_P2   = alloc((size_t)PVOX * 32 * 2);   // 18.4 MB (zeroed sweep end)

  int*   flag   = (int*)(ws + o_flag);
  int*   cnt    = (int*)(ws + o_cnt);
  float* m1f    = (float*)(ws + o_m1f);
  float* wbuf   = (float*)(ws + o_wbuf);
  short* WI     = (short*)(ws + o_WI);
  int*   list   = (int*)(ws + o_list);
  int*   idxvol = (int*)(ws + o_idx);
  short* xc     = (short*)(ws + o_xc);
  short* h0c    = (short*)(ws + o_h0c);
  short* h1c    = (short*)(ws + o_h1c);
  short* P1     = (short*)(ws + o_P1);
  short* P2     = (short*)(ws + o_P2);

  hipMemsetAsync(cnt, 0, 4, stream);
  hipMemsetAsync(idxvol, 0xFF, (size_t)PH3 * 4, stream);
  // zero xc + h0c + h1c + P1 + P2 in one contiguous sweep (~65 MB)
  hipMemsetAsync(ws + o_xc, 0, (o_P2 - o_xc) + (size_t)PVOX * 32 * 2, stream);

  probe_k<<<1, 64, 0, stream>>>((const unsigned*)s0a, flag);
  cvt_k<<<(WTOT + 255) / 256, 256, 0, stream>>>(w0a, w0b, wd0, w1a, w1b,
                                                s0a, b0a, s0b, b0b, sd0, bd0,
                                                s1a, b1a, s1b, b1b, flag, wbuf);
  wtrans_k<<<108, 256, 0, stream>>>(wbuf, WI);
  masklist_k<<<256, 256, 0, stream>>>(mask, list, idxvol, cnt);
  dsmask_k<<<M3 / 256, 256, 0, stream>>>(mask, m1f);

  pack_c_k<<<1024, 256, 0, stream>>>(xf, flag, list, cnt, xc);
  conv0a_mfma_k<<<1024, 256, 0, stream>>>(xc, idxvol, list, cnt, WI, wbuf, h0c);
  conv0b_mfma_k<<<1024, 256, 0, stream>>>(h0c, idxvol, list, cnt, WI, wbuf, h1c);
  convd0_mfma_k<<<1024, 256, 0, stream>>>(h1c, idxvol, m1f, WI, wbuf, P1);

  conv1_mfma_k<<<512, 256, 0, stream>>>(P1, P2, WI + IW1A, wbuf, OS1A, OB1A, m1f);
  conv1_mfma_k<<<512, 256, 0, stream>>>(P2, P1, WI + IW1B, wbuf, OS1B, OB1B, m1f);

  sample_k<<<NPTS / 256, 256, 0, stream>>>(coords, flag, P1, d_out);
}